// Round 7
// baseline (109.521 us; speedup 1.0000x reference)
//
#include <hip/hip_runtime.h>

// Problem constants (B=8, K=8192 from setup_inputs).
#define KPTS 8192
#define BATCH 8
#define TPB 256

#define ACC 16                       // adv points per thread (2x R6: halves LDS reads/pair)
#define M_TILE (ACC * TPB)           // 4096
#define MT (KPTS / M_TILE)           // 2 m-tiles per batch
#define NT 64                        // n-slices per batch
#define N_SLICE (KPTS / NT)          // 128
#define GRID_A (BATCH * MT * NT)     // 1024 blocks = 4/CU

#define SB 32                        // phaseB blocks per batch
#define GRID_B (BATCH * SB)          // 256 blocks; each owns TPB m-points

// Scratch in device globals: every element overwritten before read on every
// call => no init pass, no atomics, graph-replay idempotent.
__device__ float g_ws[(size_t)BATCH * NT * KPTS];   // 16.8 MB partial mins
__device__ float g_partial[GRID_B];                 // per-block maxes

// ---- phaseA: per (b, m-tile, n-slice) partial min, plain stores ----------
__global__ __launch_bounds__(TPB) void phaseA(const float* __restrict__ adv,
                                              const float* __restrict__ ori) {
    __shared__ float4 sO[N_SLICE];   // (x, y, z, ||o||^2)

    const int bid = blockIdx.x;
    const int b  = bid >> 7;                 // / (MT*NT) = /128
    const int mt = (bid >> 6) & (MT - 1);
    const int nt = bid & (NT - 1);
    const int tid = threadIdx.x;

    const float* op = ori + ((size_t)b * KPTS + (size_t)nt * N_SLICE) * 3;
    if (tid < N_SLICE) {
        float x = op[3 * tid + 0];
        float y = op[3 * tid + 1];
        float z = op[3 * tid + 2];
        sO[tid] = make_float4(x, y, z, x * x + y * y + z * z);
    }

    float nax[ACC], nay[ACC], naz[ACC], mn[ACC];
    const float* ap = adv + ((size_t)b * KPTS + (size_t)mt * M_TILE) * 3;
#pragma unroll
    for (int i = 0; i < ACC; ++i) {
        int m = tid + i * TPB;               // tile-local adv index
        nax[i] = -2.0f * ap[3 * m + 0];
        nay[i] = -2.0f * ap[3 * m + 1];
        naz[i] = -2.0f * ap[3 * m + 2];
        mn[i]  = __builtin_huge_valf();
    }
    __syncthreads();

    // 3.5 VALU/pair; 2 broadcast ds_read_b128 feed 2*ACC=32 pairs/lane
    // (1 B LDS per pair — below the ~12cyc/b128 return-path budget).
    // Software-pipelined: prefetch n+2/n+3 (mask-wrapped, branch-free)
    // so the ds_read issues ~2 VALU-bursts ahead of its first use.
    float4 c0 = sO[0], c1 = sO[1];
#pragma unroll 2
    for (int n = 0; n < N_SLICE; n += 2) {
        float4 p0 = sO[(n + 2) & (N_SLICE - 1)];
        float4 p1 = sO[(n + 3) & (N_SLICE - 1)];
#pragma unroll
        for (int i = 0; i < ACC; ++i) {
            float t0 = fmaf(naz[i], c0.z, fmaf(nay[i], c0.y, fmaf(nax[i], c0.x, c0.w)));
            float t1 = fmaf(naz[i], c1.z, fmaf(nay[i], c1.y, fmaf(nax[i], c1.x, c1.w)));
            mn[i] = fminf(mn[i], fminf(t0, t1));   // -> v_min3_f32
        }
        c0 = p0; c1 = p1;
    }

    // Plain coalesced stores; ||a||^2 recomputed here (L1/L2-hit refetch)
    // to keep inner-loop VGPRs low.
    float* wsb = g_ws + ((size_t)(b * NT + nt)) * KPTS + (size_t)mt * M_TILE;
#pragma unroll
    for (int i = 0; i < ACC; ++i) {
        int m = tid + i * TPB;               // tile-local
        float x = ap[3 * m + 0];
        float y = ap[3 * m + 1];
        float z = ap[3 * m + 2];
        float aa = fmaf(x, x, fmaf(y, y, z * z));
        wsb[m] = mn[i] + aa;
    }
}

// ---- phaseB: min over NT slices, block max-reduce, one partial per block --
__global__ __launch_bounds__(TPB) void phaseB() {
    const int blk = blockIdx.x;              // GRID_B = B * SB
    const int b   = blk / SB;
    const int sb  = blk % SB;
    const int tid = threadIdx.x;
    const int m   = sb * TPB + tid;          // this thread's adv point

    const float* base = g_ws + ((size_t)b * NT) * KPTS + m;
    float m0 = __builtin_huge_valf(), m1 = m0, m2 = m0, m3 = m0;
#pragma unroll
    for (int t = 0; t < NT; t += 4) {        // 4 independent min chains (MLP)
        m0 = fminf(m0, base[(size_t)(t + 0) * KPTS]);
        m1 = fminf(m1, base[(size_t)(t + 1) * KPTS]);
        m2 = fminf(m2, base[(size_t)(t + 2) * KPTS]);
        m3 = fminf(m3, base[(size_t)(t + 3) * KPTS]);
    }
    float v = fminf(fminf(m0, m1), fminf(m2, m3));   // min_n dist^2 for m

#pragma unroll
    for (int off = 32; off; off >>= 1)
        v = fmaxf(v, __shfl_down(v, off, 64));

    __shared__ float red[TPB / 64];
    if ((tid & 63) == 0) red[tid >> 6] = v;
    __syncthreads();
    if (tid == 0)
        g_partial[blk] = fmaxf(fmaxf(red[0], red[1]), fmaxf(red[2], red[3]));
}

// ---- phaseC: single wave -> weighted mean, single writer ------------------
__global__ void phaseC(const float* __restrict__ w, float* __restrict__ out) {
    const int tid = threadIdx.x;             // 64 threads
    float v = 0.0f;
    if (tid < BATCH) {
        float mx = -__builtin_huge_valf();
#pragma unroll
        for (int i = 0; i < SB; ++i)
            mx = fmaxf(mx, g_partial[tid * SB + i]);
        v = mx * w[tid] * (1.0f / BATCH);
    }
#pragma unroll
    for (int off = 4; off; off >>= 1)        // sum lanes 0..7
        v += __shfl_down(v, off, 64);
    if (tid == 0) out[0] = v;
}

extern "C" void kernel_launch(void* const* d_in, const int* in_sizes, int n_in,
                              void* d_out, int out_size, void* d_ws, size_t ws_size,
                              hipStream_t stream) {
    const float* adv = (const float*)d_in[0];   // [B, K, 3]
    const float* ori = (const float*)d_in[1];   // [B, K, 3]
    const float* w   = (const float*)d_in[2];   // [B]
    float* out = (float*)d_out;
    (void)d_ws; (void)ws_size;

    phaseA<<<GRID_A, TPB, 0, stream>>>(adv, ori);
    phaseB<<<GRID_B, TPB, 0, stream>>>();
    phaseC<<<1, 64, 0, stream>>>(w, out);
}